// Round 8
// baseline (32.213 us; speedup 1.0000x reference)
//
#include <hip/hip_runtime.h>
#include <hip/hip_bf16.h>

using u32 = unsigned int;
using u16 = unsigned short;

typedef __attribute__((ext_vector_type(8))) _Float16 half8;
typedef __attribute__((ext_vector_type(2))) _Float16 half2v;
typedef __attribute__((ext_vector_type(16))) float f32x16;
typedef __attribute__((ext_vector_type(4))) u32 u32x4;

#define IN_K   4096
#define OUT_N  14336
#define SPLITK 8
#define NSTAGE 4                 // 4 stages x 128k = 512k per block
#define OUT_ELEMS (64 * OUT_N)   // 917504

// ---------------------------------------------------------------------------
// prep: x f32[64][4096] -> xs f16 in MFMA-fragment order.
// xs layout: [512 chunks][64 rows][8 f16]; chunk c covers k = 8c + perm[j],
// perm = {0,4,1,5,2,6,3,7} (matches pair-dequant element order).
__global__ __launch_bounds__(256) void prep_kernel(const float* __restrict__ x,
                                                   u16* __restrict__ xs) {
  const int t = blockIdx.x * 256 + threadIdx.x;   // 32768 threads
  const int c = t >> 6;        // chunk 0..511
  const int r = t & 63;        // row
  const float* px = x + r * IN_K + c * 8;
  const float4 a = *(const float4*)px;
  const float4 b = *(const float4*)(px + 4);
  const float af[4] = {a.x, a.y, a.z, a.w};
  const float bf[4] = {b.x, b.y, b.z, b.w};
  union { u32x4 v; u32 u[4]; } o;
#pragma unroll
  for (int i = 0; i < 4; ++i) {
    const _Float16 hl = (_Float16)af[i];   // k = 8c + i
    const _Float16 hh = (_Float16)bf[i];   // k = 8c + i + 4
    u16 lo, hi;
    __builtin_memcpy(&lo, &hl, 2);
    __builtin_memcpy(&hi, &hh, 2);
    o.u[i] = (u32)lo | ((u32)hi << 16);
  }
  *(u32x4*)(xs + (size_t)t * 8) = o.v;
}

// ---------------------------------------------------------------------------
__global__ __launch_bounds__(256) void bias_init_kernel(const float* __restrict__ bias,
                                                        float* __restrict__ out) {
  const int i = (blockIdx.x * 256 + threadIdx.x) * 4;
  const int col = i % OUT_N;
  *(float4*)(out + i) = *(const float4*)(bias + col);
}

// reduce: grid (112, 8). Block (gx, ry): bx = gx>>1 (256-col tile), half = gx&1.
// Partials tiled [bx(56)][by(8)][64 rows][256 cols].
__global__ __launch_bounds__(256) void reduce_kernel(const float* __restrict__ part,
                                                     const float* __restrict__ bias,
                                                     float* __restrict__ out) {
  const int gx = blockIdx.x, ry = blockIdx.y, t = threadIdx.x;
  const int bx = gx >> 1, half = gx & 1;
  const int row = ry * 8 + (t >> 5);
  const int cin = half * 128 + (t & 31) * 4;
  const float* p = part + (((size_t)bx * SPLITK) * 64 + row) * 256 + cin;
  float4 r = *(const float4*)(bias + bx * 256 + cin);
#pragma unroll
  for (int by = 0; by < SPLITK; ++by) {
    const float4 a = *(const float4*)(p + (size_t)by * 64 * 256);
    r.x += a.x; r.y += a.y; r.z += a.z; r.w += a.w;
  }
  *(float4*)(out + (size_t)row * OUT_N + bx * 256 + cin) = r;
}

// dequant one qweight word (8 weights, fragment order) -> f16x8 B-fragment
static __device__ __forceinline__ half8 dequant8(u32 q, half2v hz, half2v s2) {
  const u32 p0 = (q & 0x000F000Fu) | 0x64006400u;          // (n0,n4)+1024
  const u32 p1 = ((q >> 4) & 0x000F000Fu) | 0x64006400u;   // (n1,n5)+1024
  const u32 p2 = ((q >> 8) & 0x000F000Fu) | 0x64006400u;   // (n2,n6)+1024
  const u32 p3 = ((q >> 12) & 0x000F000Fu) | 0x64006400u;  // (n3,n7)+1024
  half2v t0, t1, t2, t3;
  __builtin_memcpy(&t0, &p0, 4);
  __builtin_memcpy(&t1, &p1, 4);
  __builtin_memcpy(&t2, &p2, 4);
  __builtin_memcpy(&t3, &p3, 4);
  union { half8 v; half2v h[4]; } bb;
  bb.h[0] = (t0 - hz) * s2;    // exact int sub, then scale (v_pk_*_f16)
  bb.h[1] = (t1 - hz) * s2;
  bb.h[2] = (t2 - hz) * s2;
  bb.h[3] = (t3 - hz) * s2;
  return bb.v;
}

// ---------------------------------------------------------------------------
// qgemm: grid (56, 8), 4 waves/block. Wave = 64 cols x 64 rows x 512 k
// (4 accumulators; one A fragment pair feeds 4 MFMAs -> 40% less LDS read,
// half the stages/barriers of the 32-col version). A+Q staged to LDS via
// global_load_lds width-16, double-buffered, counted vmcnt(8).
template <bool ATOMIC>
__global__ __launch_bounds__(256, 2) void qgemm_kernel(
    const u32* __restrict__ qw, const u32* __restrict__ qz,
    const float* __restrict__ scal, const u16* __restrict__ xs,
    float* __restrict__ dst) {
  __shared__ u16 alds[2][8192];            // 2 x 16 KB A stages
  __shared__ u32 qlds[2][4096];            // 2 x 16 KB Q stages (16 rows x 256)
  const int tid = threadIdx.x;
  const int lane = tid & 63;
  const int wv = tid >> 6;
  const int g = lane >> 5;                 // k-half within 16k step
  const int nn = lane & 31;
  const int bx = blockIdx.x;
  const int by = blockIdx.y;
  const int colw = wv * 64;                // wave col base within 256-col tile
  const int col0 = bx * 256 + colw + nn;   // absolute col, half 0
  const int col1 = col0 + 32;              // absolute col, half 1
  const int chunk0 = by * 64;              // 8k-chunk base (== qw row base)
  const int grp0 = by * NSTAGE;            // 4 quant groups per block
  const int zsh = (nn & 7) * 4;            // same for both halves (32|8 aligned)

  f32x16 acc00, acc01, acc10, acc11;
#pragma unroll
  for (int i = 0; i < 16; ++i) { acc00[i] = 0.f; acc01[i] = 0.f;
                                 acc10[i] = 0.f; acc11[i] = 0.f; }

  // ---- scales & zero-words for all 4 groups x 2 col-halves -> registers ----
  float sv0[NSTAGE], sv1[NSTAGE]; u32 zv0[NSTAGE], zv1[NSTAGE];
#pragma unroll
  for (int t = 0; t < NSTAGE; ++t) {
    sv0[t] = scal[(size_t)(grp0 + t) * OUT_N + col0];
    sv1[t] = scal[(size_t)(grp0 + t) * OUT_N + col1];
    zv0[t] = qz[(size_t)(grp0 + t) * (OUT_N / 8) + (col0 >> 3)];
    zv1[t] = qz[(size_t)(grp0 + t) * (OUT_N / 8) + (col1 >> 3)];
  }
  // drain scalar loads so per-stage vmcnt counts ONLY staging loads
  asm volatile("s_waitcnt vmcnt(0)" ::: "memory");

  // ---- stage issue: A (4 instr/thread) + Q (4 instr/thread) = 8/wave ----
  auto issue = [&](int st) {
    const u16* asrc = xs + (size_t)(chunk0 + st * 16) * 512;   // 16 KB linear
    u16* adst = &alds[st & 1][0];
#pragma unroll
    for (int r = 0; r < 4; ++r) {
      const int p = r * 256 + tid;
      __builtin_amdgcn_global_load_lds(
          (const __attribute__((address_space(1))) void*)(asrc + p * 8),
          (__attribute__((address_space(3))) void*)(adst + p * 8), 16, 0, 0);
    }
    // Q tile: rows chunk0+st*16+j (j=0..15), cols bx*256..+256 (1 KB/row)
    const u32* qsrc = qw + (size_t)(chunk0 + st * 16) * OUT_N + bx * 256;
    u32* qdst = &qlds[st & 1][0];
#pragma unroll
    for (int r = 0; r < 4; ++r) {
      const int p = r * 256 + tid;           // 0..1023 16B-chunks
      const int j = p >> 6;                  // row 0..15
      const int cg = p & 63;                 // 16B col-group
      __builtin_amdgcn_global_load_lds(
          (const __attribute__((address_space(1))) void*)(qsrc + (size_t)j * OUT_N + cg * 4),
          (__attribute__((address_space(3))) void*)(qdst + p * 4), 16, 0, 0);
    }
  };

  issue(0);

#pragma unroll
  for (int st = 0; st < NSTAGE; ++st) {
    if (st == 0) {
      issue(1);                                        // outstanding 16
      asm volatile("s_waitcnt vmcnt(8)" ::: "memory"); // stage 0 complete
    } else if (st < NSTAGE - 1) {
      __builtin_amdgcn_s_barrier();                    // WAR on buf[(st+1)&1]
      issue(st + 1);                                   // 8 + 8
      asm volatile("s_waitcnt vmcnt(8)" ::: "memory"); // stage st complete
    } else {
      __builtin_amdgcn_s_barrier();
      asm volatile("s_waitcnt vmcnt(0)" ::: "memory");
    }
    __builtin_amdgcn_s_barrier();                      // stage st visible
    asm volatile("" ::: "memory");

    // dequant constants for this group (GROUP = 128 k = 1 stage)
    const u32 zq0 = (zv0[st] >> zsh) & 0xFu;
    const u32 zq1 = (zv1[st] >> zsh) & 0xFu;
    const u32 hzu0 = 0x64016401u + zq0 * 0x00010001u;  // f16x2 of (1025+z)
    const u32 hzu1 = 0x64016401u + zq1 * 0x00010001u;
    half2v hz0, hz1;
    __builtin_memcpy(&hz0, &hzu0, 4);
    __builtin_memcpy(&hz1, &hzu1, 4);
    const _Float16 hs0 = (_Float16)sv0[st];
    const _Float16 hs1 = (_Float16)sv1[st];
    const half2v s20 = {hs0, hs0};
    const half2v s21 = {hs1, hs1};

    const u16* abuf = &alds[st & 1][0];
    const u32* qbuf = &qlds[st & 1][0];
#pragma unroll
    for (int s = 0; s < 8; ++s) {
      const int cl = s * 2 + g;
      const half8 a0 = *(const half8*)(abuf + (cl * 64 + nn) * 8);
      const half8 a1 = *(const half8*)(abuf + (cl * 64 + nn + 32) * 8);
      const u32 q0 = qbuf[cl * 256 + colw + nn];
      const u32 q1 = qbuf[cl * 256 + colw + nn + 32];
      const half8 bb0 = dequant8(q0, hz0, s20);
      const half8 bb1 = dequant8(q1, hz1, s21);
      acc00 = __builtin_amdgcn_mfma_f32_32x32x16_f16(a0, bb0, acc00, 0, 0, 0);
      acc10 = __builtin_amdgcn_mfma_f32_32x32x16_f16(a1, bb0, acc10, 0, 0, 0);
      acc01 = __builtin_amdgcn_mfma_f32_32x32x16_f16(a0, bb1, acc01, 0, 0, 0);
      acc11 = __builtin_amdgcn_mfma_f32_32x32x16_f16(a1, bb1, acc11, 0, 0, 0);
    }
  }

  // C/D layout: col = lane&31, row = (r&3) + 8*(r>>2) + 4*(lane>>5)
  if (ATOMIC) {
#pragma unroll
    for (int r = 0; r < 16; ++r) {
      const int row = (r & 3) + 8 * (r >> 2) + 4 * g;
      unsafeAtomicAdd(&dst[(size_t)row * OUT_N + col0], acc00[r]);
      unsafeAtomicAdd(&dst[(size_t)row * OUT_N + col1], acc01[r]);
      unsafeAtomicAdd(&dst[(size_t)(row + 32) * OUT_N + col0], acc10[r]);
      unsafeAtomicAdd(&dst[(size_t)(row + 32) * OUT_N + col1], acc11[r]);
    }
  } else {
    // tiled partials: [bx][by][64][256], 64 KB contiguous per block
    float* p = dst + (((size_t)bx * SPLITK + by) * 64) * 256 + colw + nn;
#pragma unroll
    for (int r = 0; r < 16; ++r) {
      const int row = (r & 3) + 8 * (r >> 2) + 4 * g;
      p[(size_t)row * 256]        = acc00[r];
      p[(size_t)row * 256 + 32]   = acc01[r];
      p[(size_t)(row + 32) * 256]      = acc10[r];
      p[(size_t)(row + 32) * 256 + 32] = acc11[r];
    }
  }
}

// ---------------------------------------------------------------------------
extern "C" void kernel_launch(void* const* d_in, const int* in_sizes, int n_in,
                              void* d_out, int out_size, void* d_ws, size_t ws_size,
                              hipStream_t stream) {
  (void)in_sizes; (void)n_in; (void)out_size;
  const float* x    = (const float*)d_in[0];
  const u32*   qw   = (const u32*)d_in[1];
  const u32*   qz   = (const u32*)d_in[2];
  const float* sc   = (const float*)d_in[3];
  const float* bias = (const float*)d_in[4];
  // d_in[5] = g_idx: sequential k/128 for this problem; folded into indexing.
  float* out = (float*)d_out;

  const size_t XS_BYTES   = (size_t)64 * IN_K * 2;                 // 512 KB
  const size_t PART_BYTES = (size_t)56 * SPLITK * 64 * 256 * 4;    // 29.36 MB
  u16* xs = (u16*)d_ws;

  prep_kernel<<<128, 256, 0, stream>>>(x, xs);

  if (ws_size >= XS_BYTES + PART_BYTES) {
    float* part = (float*)((char*)d_ws + XS_BYTES);
    qgemm_kernel<false><<<dim3(56, SPLITK), 256, 0, stream>>>(qw, qz, sc, xs, part);
    reduce_kernel<<<dim3(112, 8), 256, 0, stream>>>(part, bias, out);
  } else {
    bias_init_kernel<<<896, 256, 0, stream>>>(bias, out);
    qgemm_kernel<true><<<dim3(56, SPLITK), 256, 0, stream>>>(qw, qz, sc, xs, out);
  }
}

// Round 9
// 31.620 us; speedup vs baseline: 1.0187x; 1.0187x over previous
//
#include <hip/hip_runtime.h>
#include <hip/hip_bf16.h>

using u32 = unsigned int;
using u16 = unsigned short;

typedef __attribute__((ext_vector_type(8))) _Float16 half8;
typedef __attribute__((ext_vector_type(2))) _Float16 half2v;
typedef __attribute__((ext_vector_type(16))) float f32x16;
typedef __attribute__((ext_vector_type(4))) u32 u32x4;

#define IN_K   4096
#define OUT_N  14336
#define SPLITK 8
#define OUT_ELEMS (64 * OUT_N)   // 917504

// ---------------------------------------------------------------------------
// prep: x f32[64][4096] -> xs f16 in MFMA-fragment order.
// xs layout: [512 chunks][64 rows][8 f16]; chunk c covers k = 8c + perm[j],
// perm = {0,4,1,5,2,6,3,7} (matches pair-dequant element order).
__global__ __launch_bounds__(256) void prep_kernel(const float* __restrict__ x,
                                                   u16* __restrict__ xs) {
  const int t = blockIdx.x * 256 + threadIdx.x;   // 32768 threads
  const int c = t >> 6;        // chunk 0..511
  const int r = t & 63;        // row
  const float* px = x + r * IN_K + c * 8;
  const float4 a = *(const float4*)px;
  const float4 b = *(const float4*)(px + 4);
  const float af[4] = {a.x, a.y, a.z, a.w};
  const float bf[4] = {b.x, b.y, b.z, b.w};
  union { u32x4 v; u32 u[4]; } o;
#pragma unroll
  for (int i = 0; i < 4; ++i) {
    const _Float16 hl = (_Float16)af[i];   // k = 8c + i
    const _Float16 hh = (_Float16)bf[i];   // k = 8c + i + 4
    u16 lo, hi;
    __builtin_memcpy(&lo, &hl, 2);
    __builtin_memcpy(&hi, &hh, 2);
    o.u[i] = (u32)lo | ((u32)hi << 16);
  }
  *(u32x4*)(xs + (size_t)t * 8) = o.v;
}

// ---------------------------------------------------------------------------
__global__ __launch_bounds__(256) void bias_init_kernel(const float* __restrict__ bias,
                                                        float* __restrict__ out) {
  const int i = (blockIdx.x * 256 + threadIdx.x) * 4;
  const int col = i % OUT_N;
  *(float4*)(out + i) = *(const float4*)(bias + col);
}

// reduce: grid (112, 8). Block (gx, ry): bx = gx>>1 (256-col tile), half = gx&1.
// Partials tiled [bx(56)][by(8)][64 rows][256 cols].
__global__ __launch_bounds__(256) void reduce_kernel(const float* __restrict__ part,
                                                     const float* __restrict__ bias,
                                                     float* __restrict__ out) {
  const int gx = blockIdx.x, ry = blockIdx.y, t = threadIdx.x;
  const int bx = gx >> 1, half = gx & 1;
  const int row = ry * 8 + (t >> 5);
  const int cin = half * 128 + (t & 31) * 4;
  const float* p = part + (((size_t)bx * SPLITK) * 64 + row) * 256 + cin;
  float4 r = *(const float4*)(bias + bx * 256 + cin);
#pragma unroll
  for (int by = 0; by < SPLITK; ++by) {
    const float4 a = *(const float4*)(p + (size_t)by * 64 * 256);
    r.x += a.x; r.y += a.y; r.z += a.z; r.w += a.w;
  }
  *(float4*)(out + (size_t)row * OUT_N + bx * 256 + cin) = r;
}

// dequant one qweight word (8 weights, fragment order) -> f16x8 B-fragment
static __device__ __forceinline__ half8 dequant8(u32 q, half2v hz, half2v s2) {
  const u32 p0 = (q & 0x000F000Fu) | 0x64006400u;          // (n0,n4)+1024
  const u32 p1 = ((q >> 4) & 0x000F000Fu) | 0x64006400u;   // (n1,n5)+1024
  const u32 p2 = ((q >> 8) & 0x000F000Fu) | 0x64006400u;   // (n2,n6)+1024
  const u32 p3 = ((q >> 12) & 0x000F000Fu) | 0x64006400u;  // (n3,n7)+1024
  half2v t0, t1, t2, t3;
  __builtin_memcpy(&t0, &p0, 4);
  __builtin_memcpy(&t1, &p1, 4);
  __builtin_memcpy(&t2, &p2, 4);
  __builtin_memcpy(&t3, &p3, 4);
  union { half8 v; half2v h[4]; } bb;
  bb.h[0] = (t0 - hz) * s2;    // exact int sub, then scale (v_pk_*_f16)
  bb.h[1] = (t1 - hz) * s2;
  bb.h[2] = (t2 - hz) * s2;
  bb.h[3] = (t3 - hz) * s2;
  return bb.v;
}

// ---------------------------------------------------------------------------
// qgemm: grid (56, 8), 8 waves/block (512 thr). Wave = 32 cols x 64 rows x 512 k.
// A panel (64 KB) staged to LDS ONCE in the prologue -> ONE barrier total.
// K-loop is barrier-free: Q streams per-wave through a depth-4 register ring
// (compiler-managed waits), dequant in-register to f16, 2 MFMA/step.
// Occupancy: 2 blocks/CU (64 KB LDS) = 16 waves/CU = 4 waves/SIMD.
template <bool ATOMIC>
__global__ __launch_bounds__(512, 4) void qgemm_kernel(
    const u32* __restrict__ qw, const u32* __restrict__ qz,
    const float* __restrict__ scal, const u16* __restrict__ xs,
    float* __restrict__ dst) {
  __shared__ u16 alds[64 * 512];           // 64 KB: [64 chunks][64 rows][8 f16]
  const int tid = threadIdx.x;             // 0..511
  const int lane = tid & 63;
  const int wv = tid >> 6;                 // 0..7
  const int g = lane >> 5;                 // k-half within 16k step
  const int nn = lane & 31;
  const int bx = blockIdx.x;
  const int by = blockIdx.y;
  const int colabs = bx * 256 + wv * 32 + nn;
  const int chunk0 = by * 64;              // 8k-chunk base (== qw row base)
  const int grp0 = by * 4;                 // 4 quant groups per block
  const int zsh = (nn & 7) * 4;

  f32x16 acc0, acc1;
#pragma unroll
  for (int i = 0; i < 16; ++i) { acc0[i] = 0.f; acc1[i] = 0.f; }

  // ---- prologue: stage whole A panel (64 KB) to LDS ----
  const u16* asrc = xs + (size_t)chunk0 * 512;       // contiguous 64 KB
#pragma unroll
  for (int r = 0; r < 8; ++r) {
    const int p = r * 512 + tid;                     // 16B chunk id
    __builtin_amdgcn_global_load_lds(
        (const __attribute__((address_space(1))) void*)(asrc + p * 8),
        (__attribute__((address_space(3))) void*)(&alds[0] + p * 8), 16, 0, 0);
  }

  // scales & zero-words for the 4 groups -> registers
  float sv[4]; u32 zv[4];
#pragma unroll
  for (int t = 0; t < 4; ++t) {
    sv[t] = scal[(size_t)(grp0 + t) * OUT_N + colabs];
    zv[t] = qz[(size_t)(grp0 + t) * (OUT_N / 8) + (colabs >> 3)];
  }

  // Q register ring, depth 4 (step t reads qw row chunk0 + 2t + g)
  const u32* pq = qw + (size_t)(chunk0 + g) * OUT_N + colabs;
  u32 qr[4];
#pragma unroll
  for (int i = 0; i < 4; ++i) qr[i] = pq[(size_t)i * 2 * OUT_N];

  asm volatile("s_waitcnt vmcnt(0)" ::: "memory");   // A panel + consts ready
  __builtin_amdgcn_s_barrier();                      // the ONLY barrier
  asm volatile("" ::: "memory");

  // ---- barrier-free K loop: 4 groups x 8 steps, fully unrolled ----
#pragma unroll
  for (int grp = 0; grp < 4; ++grp) {
    const u32 zq = (zv[grp] >> zsh) & 0xFu;
    const u32 hzu = 0x64016401u + zq * 0x00010001u;  // f16x2 of (1025+z)
    half2v hz; __builtin_memcpy(&hz, &hzu, 4);
    const _Float16 hs = (_Float16)sv[grp];
    const half2v s2 = {hs, hs};
#pragma unroll
    for (int s = 0; s < 8; ++s) {
      const int t = grp * 8 + s;
      const int cl = 2 * t + g;                      // k-chunk for this half
      const half8 a0 = *(const half8*)(&alds[0] + ((size_t)cl * 64 + nn) * 8);
      const half8 a1 = *(const half8*)(&alds[0] + ((size_t)cl * 64 + nn + 32) * 8);
      const u32 q = qr[t & 3];
      if (t + 4 < 32)                                // refill ring (static idx)
        qr[t & 3] = pq[(size_t)(t + 4) * 2 * OUT_N];
      const half8 bb = dequant8(q, hz, s2);
      acc0 = __builtin_amdgcn_mfma_f32_32x32x16_f16(a0, bb, acc0, 0, 0, 0);
      acc1 = __builtin_amdgcn_mfma_f32_32x32x16_f16(a1, bb, acc1, 0, 0, 0);
    }
  }

  // C/D layout: col = lane&31, row = (r&3) + 8*(r>>2) + 4*(lane>>5)
  if (ATOMIC) {
#pragma unroll
    for (int r = 0; r < 16; ++r) {
      const int row = (r & 3) + 8 * (r >> 2) + 4 * g;
      unsafeAtomicAdd(&dst[(size_t)row * OUT_N + colabs], acc0[r]);
      unsafeAtomicAdd(&dst[(size_t)(row + 32) * OUT_N + colabs], acc1[r]);
    }
  } else {
    // tiled partials: [bx][by][64][256], 64 KB contiguous per block
    float* p = dst + (((size_t)bx * SPLITK + by) * 64) * 256 + wv * 32 + nn;
#pragma unroll
    for (int r = 0; r < 16; ++r) {
      const int row = (r & 3) + 8 * (r >> 2) + 4 * g;
      p[(size_t)row * 256] = acc0[r];
      p[(size_t)(row + 32) * 256] = acc1[r];
    }
  }
}

// ---------------------------------------------------------------------------
extern "C" void kernel_launch(void* const* d_in, const int* in_sizes, int n_in,
                              void* d_out, int out_size, void* d_ws, size_t ws_size,
                              hipStream_t stream) {
  (void)in_sizes; (void)n_in; (void)out_size;
  const float* x    = (const float*)d_in[0];
  const u32*   qw   = (const u32*)d_in[1];
  const u32*   qz   = (const u32*)d_in[2];
  const float* sc   = (const float*)d_in[3];
  const float* bias = (const float*)d_in[4];
  // d_in[5] = g_idx: sequential k/128 for this problem; folded into indexing.
  float* out = (float*)d_out;

  const size_t XS_BYTES   = (size_t)64 * IN_K * 2;                 // 512 KB
  const size_t PART_BYTES = (size_t)56 * SPLITK * 64 * 256 * 4;    // 29.36 MB
  u16* xs = (u16*)d_ws;

  prep_kernel<<<128, 256, 0, stream>>>(x, xs);

  if (ws_size >= XS_BYTES + PART_BYTES) {
    float* part = (float*)((char*)d_ws + XS_BYTES);
    qgemm_kernel<false><<<dim3(56, SPLITK), 512, 0, stream>>>(qw, qz, sc, xs, part);
    reduce_kernel<<<dim3(112, 8), 256, 0, stream>>>(part, bias, out);
  } else {
    bias_init_kernel<<<896, 256, 0, stream>>>(bias, out);
    qgemm_kernel<true><<<dim3(56, SPLITK), 512, 0, stream>>>(qw, qz, sc, xs, out);
  }
}